// Round 4
// baseline (1088.337 us; speedup 1.0000x reference)
//
#include <hip/hip_runtime.h>

typedef unsigned short u16;
using bf16x8 = __attribute__((ext_vector_type(8))) short;
using f32x4  = __attribute__((ext_vector_type(4))) float;

#define SQRT_HALF 0.70710678118f
#define TP 264   // padded LDS pos pitch (elements) for tail kernel

__device__ __forceinline__ u16 f2bf(float f) {
    union { float f; unsigned int i; } x; x.f = f;
    unsigned int i = x.i;
    unsigned int r = (i + 0x7FFFu + ((i >> 16) & 1u)) >> 16;
    return (u16)r;
}
__device__ __forceinline__ float bf2f(u16 u) {
    union { unsigned int i; float f; } x; x.i = ((unsigned int)u) << 16; return x.f;
}
__device__ __forceinline__ float sigm(float x) { return 1.0f / (1.0f + __expf(-x)); }
__device__ __forceinline__ float tanh_f(float x) {
    float cx = fminf(fmaxf(x, -12.f), 12.f);
    float e = __expf(2.f * cx);
    return (e - 1.f) / (e + 1.f);
}

// cond2[n][c] = tanh(mgc @ cond_w.T + cond_b) reshaped [400,60]  (all f32)
__global__ void cond_kernel(const float* __restrict__ mgc, const float* __restrict__ cond_w,
                            const float* __restrict__ cond_b, float* __restrict__ cond2) {
    int j = blockIdx.x * 256 + threadIdx.x;
    if (j >= 24000) return;
    int f = j / 12000, jj = j % 12000;
    float s = cond_b[jj];
    const float* wrow = cond_w + (size_t)jj * 60;
    const float* mrow = mgc + f * 60;
    for (int c = 0; c < 60; ++c) s += mrow[c] * wrow[c];
    float v = tanh_f(s);
    int n = f * 200 + jj / 60, cc = jj % 60;
    cond2[n * 60 + cc] = v;
}

// ca_in/ca_g[l][n][co] = cond2[n]·cw[l][co] + cb[l][co] + conv_bias(l,co)   (f32)
__global__ void condadd_kernel(const float* __restrict__ cond2,
                               const float* __restrict__ cw_in, const float* __restrict__ cb_in,
                               const float* __restrict__ cw_g,  const float* __restrict__ cb_g,
                               const float* __restrict__ l0_bin, const float* __restrict__ lb_in,
                               const float* __restrict__ l0_bg,  const float* __restrict__ lb_g,
                               float* __restrict__ ca_in, float* __restrict__ ca_g) {
    int idx = blockIdx.x * 256 + threadIdx.x;
    if (idx >= 10 * 400 * 256) return;
    int co = idx & 255;
    int n  = (idx >> 8) % 400;
    int l  = idx / (400 * 256);
    float si = cb_in[l * 256 + co] + (l == 0 ? l0_bin[co] : lb_in[(l - 1) * 256 + co]);
    float sg = cb_g [l * 256 + co] + (l == 0 ? l0_bg [co] : lb_g [(l - 1) * 256 + co]);
    const float* cn = cond2 + n * 60;
    const float* wi = cw_in + (size_t)(l * 256 + co) * 60;
    const float* wg = cw_g  + (size_t)(l * 256 + co) * 60;
    for (int c = 0; c < 60; ++c) {
        float cv = cn[c];
        si += cv * wi[c];
        sg += cv * wg[c];
    }
    ca_in[idx] = si;
    ca_g[idx]  = sg;
}

// Wg[l][conv][co][k*256+ci... k-major pairs] = bf16(lw_conv[l][co][ci][k])
__global__ void wreorder_kernel(const float* __restrict__ lw_in, const float* __restrict__ lw_g,
                                const float* __restrict__ lw_r, u16* __restrict__ Wg) {
    int idx = blockIdx.x * 256 + threadIdx.x;
    if (idx >= 9 * 256 * 512) return;
    int kk = idx & 511;
    int co = (idx >> 9) & 255;
    int l  = idx >> 17;
    int k = kk >> 8, ci = kk & 255;
    size_t src = ((size_t)(l * 256 + co) * 256 + ci) * 2 + k;
    size_t dst = (size_t)l * 3 * 131072 + (size_t)co * 512 + kk;
    Wg[dst]              = f2bf(lw_in[src]);
    Wg[dst + 131072]     = f2bf(lw_g[src]);
    Wg[dst + 2 * 131072] = f2bf(lw_r[src]);
}

// Layer 0 (full f32 math): Y0[n_local][t][ci] bf16, t in [0,512). uint4 stores.
__global__ void l0_kernel(const float* __restrict__ signal,
                          const float* __restrict__ l0_win, const float* __restrict__ l0_wg,
                          const float* __restrict__ l0_wr,  const float* __restrict__ l0_br,
                          const float* __restrict__ ca_in0, const float* __restrict__ ca_g0,
                          u16* __restrict__ Y0, int n_start) {
    int b = blockIdx.x;
    int tg = b & 63, n_local = b >> 6;
    int n = n_start + n_local;
    int ci0 = (threadIdx.x & 31) * 8;
    int t = tg * 8 + (threadIdx.x >> 5);
    float s0 = signal[n + 2 * t];
    float s1 = signal[n + 2 * t + 1];
    u16 ov[8];
    #pragma unroll
    for (int j = 0; j < 8; ++j) {
        int ci = ci0 + j;
        float vin = l0_win[ci * 2] * s0 + l0_win[ci * 2 + 1] * s1 + ca_in0[n * 256 + ci];
        float vg  = l0_wg [ci * 2] * s0 + l0_wg [ci * 2 + 1] * s1 + ca_g0 [n * 256 + ci];
        float vr  = l0_wr [ci * 2] * s0 + l0_wr [ci * 2 + 1] * s1 + l0_br[ci];
        ov[j] = f2bf((tanh_f(vin) * sigm(vg) + vr) * SQRT_HALF);
    }
    *(uint4*)(&Y0[((size_t)n_local * 512 + t) * 256 + ci0]) = *(uint4*)ov;
}

// Fused 3-conv GEMM + gating for layers 1..5.
// A: [M,512] bf16 row-major. Wg: [3][256][512] bf16. Out: Y [M,256] bf16.
// 512 threads, tile 256M x 64co x 3conv, BK=64.
__global__ __launch_bounds__(512, 2) void gemm_layer_kernel(
        const u16* __restrict__ A, const u16* __restrict__ Wg,
        const float* __restrict__ ca_in, const float* __restrict__ ca_g,
        const float* __restrict__ br, u16* __restrict__ Y,
        int M, int lg, int n_start) {
    __shared__ u16 Alds[256 * 72];
    __shared__ u16 Blds[192 * 72];
    int m0  = blockIdx.x * 256;
    int co0 = blockIdx.y * 64;
    int tid = threadIdx.x;
    int lane = tid & 63, wave = tid >> 6;
    int wm = wave & 3, wc = wave >> 2;
    int q = lane >> 4, r16 = lane & 15;

    f32x4 acc[3][4][2] = {};

    for (int kt = 0; kt < 8; ++kt) {
        // stage A tile [256][64]
        #pragma unroll
        for (int i = 0; i < 4; ++i) {
            int chunk = tid + i * 512;
            int row = chunk >> 3, c8 = chunk & 7;
            int m = m0 + row;
            int msafe = m < M ? m : (M - 1);
            uint4 v = *(const uint4*)(A + (size_t)msafe * 512 + kt * 64 + c8 * 8);
            *(uint4*)(&Alds[row * 72 + c8 * 8]) = v;
        }
        // stage B tiles: 3 convs x 64 co x 64 k
        #pragma unroll
        for (int i = 0; i < 3; ++i) {
            int chunk = tid + i * 512;
            int row = chunk >> 3, c8 = chunk & 7;
            int conv = row >> 6, col = row & 63;
            uint4 v = *(const uint4*)(Wg + ((size_t)conv * 256 + co0 + col) * 512 + kt * 64 + c8 * 8);
            *(uint4*)(&Blds[row * 72 + c8 * 8]) = v;
        }
        __syncthreads();
        #pragma unroll
        for (int ks = 0; ks < 2; ++ks) {
            int koff = ks * 32 + q * 8;
            bf16x8 af[4], bfr[3][2];
            #pragma unroll
            for (int ms = 0; ms < 4; ++ms)
                af[ms] = *(const bf16x8*)(&Alds[(wm * 64 + ms * 16 + r16) * 72 + koff]);
            #pragma unroll
            for (int cv = 0; cv < 3; ++cv)
                #pragma unroll
                for (int cs = 0; cs < 2; ++cs)
                    bfr[cv][cs] = *(const bf16x8*)(&Blds[(cv * 64 + wc * 32 + cs * 16 + r16) * 72 + koff]);
            #pragma unroll
            for (int cv = 0; cv < 3; ++cv)
                #pragma unroll
                for (int ms = 0; ms < 4; ++ms)
                    #pragma unroll
                    for (int cs = 0; cs < 2; ++cs)
                        acc[cv][ms][cs] = __builtin_amdgcn_mfma_f32_16x16x32_bf16(
                            af[ms], bfr[cv][cs], acc[cv][ms][cs], 0, 0, 0);
        }
        __syncthreads();
    }

    #pragma unroll
    for (int ms = 0; ms < 4; ++ms) {
        #pragma unroll
        for (int reg = 0; reg < 4; ++reg) {
            int m = m0 + wm * 64 + ms * 16 + q * 4 + reg;
            if (m >= M) continue;
            int n = n_start + (m >> lg);
            #pragma unroll
            for (int cs = 0; cs < 2; ++cs) {
                int co = co0 + wc * 32 + cs * 16 + r16;
                float vin = acc[0][ms][cs][reg] + ca_in[n * 256 + co];
                float vg  = acc[1][ms][cs][reg] + ca_g [n * 256 + co];
                float vr  = acc[2][ms][cs][reg] + br[co];
                float o = (tanh_f(vin) * sigm(vg) + vr) * SQRT_HALF;
                Y[(size_t)m * 256 + co] = f2bf(o);
            }
        }
    }
}

// ---- fused tail: layers 6..9 + head, 8 windows per block, all-LDS activations ----
template<int P_IN>
__device__ __forceinline__ void tail_layer(
        const u16* __restrict__ Wl, const float* __restrict__ ca_in_l,
        const float* __restrict__ ca_g_l, const float* __restrict__ br_l,
        const u16* Xin, u16* Xout, u16* Bst,
        int tid, int n_base, int w_n) {
    constexpr int P_OUT = P_IN / 2;
    constexpr int M_ROWS = 8 * P_OUT;
    constexpr int N_MT = (M_ROWS + 15) / 16;
    int lane = tid & 63, wave = tid >> 6;
    int q = lane >> 4, r16 = lane & 15;
    int mt = wave % N_MT;

    for (int co0 = 0; co0 < 256; co0 += 64) {
        f32x4 acc[3][4] = {};
        for (int kt = 0; kt < 4; ++kt) {          // BK=128
            #pragma unroll
            for (int i = 0; i < 12; ++i) {
                int chunk = tid + i * 256;        // 3072 = 192 rows x 16 chunks
                int row = chunk >> 4, c8 = chunk & 15;
                int conv = row >> 6, col = row & 63;
                uint4 v = *(const uint4*)(Wl + ((size_t)(conv * 256 + co0 + col)) * 512 + kt * 128 + c8 * 8);
                *(uint4*)(&Bst[row * 136 + c8 * 8]) = v;
            }
            __syncthreads();
            #pragma unroll
            for (int ks = 0; ks < 4; ++ks) {
                int kb = kt * 128 + ks * 32 + q * 8;
                int pos = kb >> 8, ch = kb & 255;
                int m = mt * 16 + r16;
                int w = (m / P_OUT) & 7, t = m % P_OUT;
                bf16x8 af = *(const bf16x8*)(&Xin[(w * P_IN + 2 * t + pos) * TP + ch]);
                int koff = ks * 32 + q * 8;
                #pragma unroll
                for (int cv = 0; cv < 3; ++cv)
                    #pragma unroll
                    for (int cs = 0; cs < 4; ++cs) {
                        bf16x8 bf = *(const bf16x8*)(&Bst[(cv * 64 + cs * 16 + r16) * 136 + koff]);
                        acc[cv][cs] = __builtin_amdgcn_mfma_f32_16x16x32_bf16(af, bf, acc[cv][cs], 0, 0, 0);
                    }
            }
            __syncthreads();
        }
        // epilogue for this co-pass
        #pragma unroll
        for (int cs = 0; cs < 4; ++cs)
            #pragma unroll
            for (int reg = 0; reg < 4; ++reg) {
                int m = mt * 16 + q * 4 + reg;
                if (m >= M_ROWS) continue;
                int w = m / P_OUT, t = m % P_OUT;
                int wc = w < w_n ? w : (w_n - 1);
                int n = n_base + wc;
                int co = co0 + cs * 16 + r16;
                float vin = acc[0][cs][reg] + ca_in_l[n * 256 + co];
                float vg  = acc[1][cs][reg] + ca_g_l [n * 256 + co];
                float vr  = acc[2][cs][reg] + br_l[co];
                float o = (tanh_f(vin) * sigm(vg) + vr) * SQRT_HALF;
                Xout[(w * P_OUT + t) * TP + co] = f2bf(o);
            }
    }
    __syncthreads();
}

__global__ __launch_bounds__(256) void tail_kernel(
        const u16* __restrict__ Y5, const u16* __restrict__ Wg,
        const float* __restrict__ ca_in, const float* __restrict__ ca_g,
        const float* __restrict__ lb_r,
        const float* __restrict__ pre_w, const float* __restrict__ pre_b,
        const float* __restrict__ mean_w, const float* __restrict__ mean_b,
        const float* __restrict__ std_w,  const float* __restrict__ std_b,
        const float* __restrict__ logit_w, const float* __restrict__ logit_b,
        float* __restrict__ out, int n_start, int n_count) {
    __shared__ u16 XA[8 * 16 * TP];   // 67584 B
    __shared__ u16 XB[8 * 8 * TP];    // 33792 B
    __shared__ u16 Bst[192 * 136];    // 52224 B
    int tid = threadIdx.x;
    int blk = blockIdx.x;
    int n_base = n_start + blk * 8;
    int w_n = n_count - blk * 8; if (w_n > 8) w_n = 8;

    // load Y5 [8 win][16 pos][256] -> XA
    #pragma unroll
    for (int i = 0; i < 16; ++i) {
        int chunk = tid + i * 256;        // 4096 = 128 rows x 32 chunks
        int row = chunk >> 5, c8 = chunk & 31;
        int w = row >> 4, pos = row & 15;
        int nl = blk * 8 + w; if (nl >= n_count) nl = n_count - 1;
        uint4 v = *(const uint4*)(Y5 + ((size_t)nl * 16 + pos) * 256 + c8 * 8);
        *(uint4*)(&XA[(w * 16 + pos) * TP + c8 * 8]) = v;
    }
    __syncthreads();

    tail_layer<16>(Wg + 5ull * 393216, ca_in + 6 * 102400, ca_g + 6 * 102400,
                   lb_r + 5 * 256, XA, XB, Bst, tid, n_base, w_n);
    tail_layer<8> (Wg + 6ull * 393216, ca_in + 7 * 102400, ca_g + 7 * 102400,
                   lb_r + 6 * 256, XB, XA, Bst, tid, n_base, w_n);
    tail_layer<4> (Wg + 7ull * 393216, ca_in + 8 * 102400, ca_g + 8 * 102400,
                   lb_r + 7 * 256, XA, XB, Bst, tid, n_base, w_n);
    tail_layer<2> (Wg + 8ull * 393216, ca_in + 9 * 102400, ca_g + 9 * 102400,
                   lb_r + 8 * 256, XB, XA, Bst, tid, n_base, w_n);

    // head (f32): pre = relu(X9 @ pre_w.T + pre_b); 3 heads of 10
    float acc8[8] = {0.f,0.f,0.f,0.f,0.f,0.f,0.f,0.f};
    int j = tid;
    for (int c = 0; c < 256; ++c) {
        float wv = pre_w[(size_t)j * 256 + c];
        #pragma unroll
        for (int w = 0; w < 8; ++w) acc8[w] += bf2f(XA[w * TP + c]) * wv;
    }
    float* pre_f = (float*)XB;
    float pb = pre_b[j];
    #pragma unroll
    for (int w = 0; w < 8; ++w) pre_f[w * 256 + j] = fmaxf(acc8[w] + pb, 0.f);
    __syncthreads();
    if (tid < 240) {
        int w = tid & 7, hm = tid >> 3;
        int head = hm / 10, mix = hm % 10;
        const float* W  = head == 0 ? mean_w : (head == 1 ? std_w : logit_w);
        const float* Bb = head == 0 ? mean_b : (head == 1 ? std_b : logit_b);
        float s = Bb[mix];
        const float* wr = W + mix * 256;
        const float* pf = pre_f + w * 256;
        for (int c = 0; c < 256; ++c) s += pf[c] * wr[c];
        if (w < w_n) out[head * 4000 + (n_base + w) * 10 + mix] = s;
    }
}

extern "C" void kernel_launch(void* const* d_in, const int* in_sizes, int n_in,
                              void* d_out, int out_size, void* d_ws, size_t ws_size,
                              hipStream_t stream) {
    const float* signal  = (const float*)d_in[0];
    const float* mgc     = (const float*)d_in[1];
    const float* cond_w  = (const float*)d_in[2];
    const float* cond_b  = (const float*)d_in[3];
    const float* l0_win  = (const float*)d_in[4];
    const float* l0_bin  = (const float*)d_in[5];
    const float* l0_wg   = (const float*)d_in[6];
    const float* l0_bg   = (const float*)d_in[7];
    const float* l0_wr   = (const float*)d_in[8];
    const float* l0_br   = (const float*)d_in[9];
    const float* lw_in   = (const float*)d_in[10];
    const float* lb_in   = (const float*)d_in[11];
    const float* lw_g    = (const float*)d_in[12];
    const float* lb_g    = (const float*)d_in[13];
    const float* lw_r    = (const float*)d_in[14];
    const float* lb_r    = (const float*)d_in[15];
    const float* cw_in   = (const float*)d_in[16];
    const float* cb_in   = (const float*)d_in[17];
    const float* cw_g    = (const float*)d_in[18];
    const float* cb_g    = (const float*)d_in[19];
    const float* pre_w   = (const float*)d_in[20];
    const float* pre_b   = (const float*)d_in[21];
    const float* mean_w  = (const float*)d_in[22];
    const float* mean_b  = (const float*)d_in[23];
    const float* std_w   = (const float*)d_in[24];
    const float* std_b   = (const float*)d_in[25];
    const float* logit_w = (const float*)d_in[26];
    const float* logit_b = (const float*)d_in[27];
    float* out = (float*)d_out;

    char* p = (char*)d_ws;
    auto alloc = [&](size_t bytes) -> char* {
        char* r = p; p += (bytes + 255) & ~(size_t)255; return r;
    };
    u16*   Wg    = (u16*)alloc(7077888);        // 9*3*256*512 bf16
    float* ca_in = (float*)alloc(4096000);      // 10*400*256 f32
    float* ca_g  = (float*)alloc(4096000);
    float* cond2 = (float*)alloc(96000);        // 400*60 f32
    size_t fixedBytes = (size_t)(p - (char*)d_ws);

    int c = 1;
    while (c < 16 && fixedBytes + (104857600ull + 52428800ull) / c + 4096 > ws_size) c <<= 1;
    u16* bufA = (u16*)alloc(104857600ull / c);
    u16* bufB = (u16*)alloc(52428800ull / c);
    int n_count = 400 / c;

    cond_kernel<<<94, 256, 0, stream>>>(mgc, cond_w, cond_b, cond2);
    condadd_kernel<<<4000, 256, 0, stream>>>(cond2, cw_in, cb_in, cw_g, cb_g,
                                             l0_bin, lb_in, l0_bg, lb_g, ca_in, ca_g);
    wreorder_kernel<<<4608, 256, 0, stream>>>(lw_in, lw_g, lw_r, Wg);

    for (int ch = 0; ch < c; ++ch) {
        int n_start = ch * n_count;
        l0_kernel<<<n_count * 64, 256, 0, stream>>>(signal, l0_win, l0_wg, l0_wr, l0_br,
                                                    ca_in, ca_g, bufA, n_start);
        u16* src = bufA;
        u16* dst = bufB;
        for (int layer = 1; layer <= 5; ++layer) {
            int lg = 9 - layer;
            int M = n_count << lg;
            dim3 grid((M + 255) / 256, 4);
            gemm_layer_kernel<<<grid, 512, 0, stream>>>(
                src, Wg + (size_t)(layer - 1) * 3 * 131072,
                ca_in + (size_t)layer * 102400, ca_g + (size_t)layer * 102400,
                lb_r + (layer - 1) * 256, dst, M, lg, n_start);
            u16* tswap = src; src = dst; dst = tswap;
        }
        // after layers 1..5 (odd count), src == bufB == Y5 [n_count*16][256]
        tail_kernel<<<(n_count + 7) / 8, 256, 0, stream>>>(
            src, Wg, ca_in, ca_g, lb_r, pre_w, pre_b, mean_w, mean_b,
            std_w, std_b, logit_w, logit_b, out, n_start, n_count);
    }
}

// Round 5
// 636.069 us; speedup vs baseline: 1.7110x; 1.7110x over previous
//
#include <hip/hip_runtime.h>

typedef unsigned short u16;
using bf16x8 = __attribute__((ext_vector_type(8))) short;
using f32x4  = __attribute__((ext_vector_type(4))) float;

#define SQRT_HALF 0.70710678118f

// async global->LDS, 16B per lane; LDS dest = wave-uniform base + lane*16
#define GLD_LDS16(gp, lp) \
    __builtin_amdgcn_global_load_lds((const __attribute__((address_space(1))) void*)(gp), \
                                     (__attribute__((address_space(3))) void*)(lp), 16, 0, 0)

__device__ __forceinline__ u16 f2bf(float f) {
    union { float f; unsigned int i; } x; x.f = f;
    unsigned int i = x.i;
    unsigned int r = (i + 0x7FFFu + ((i >> 16) & 1u)) >> 16;
    return (u16)r;
}
__device__ __forceinline__ float bf2f(u16 u) {
    union { unsigned int i; float f; } x; x.i = ((unsigned int)u) << 16; return x.f;
}
__device__ __forceinline__ float sigm(float x) { return 1.0f / (1.0f + __expf(-x)); }
__device__ __forceinline__ float tanh_f(float x) {
    float cx = fminf(fmaxf(x, -12.f), 12.f);
    float e = __expf(2.f * cx);
    return (e - 1.f) / (e + 1.f);
}

// cond2[n][c] = tanh(mgc @ cond_w.T + cond_b) reshaped [400,60]  (all f32)
__global__ void cond_kernel(const float* __restrict__ mgc, const float* __restrict__ cond_w,
                            const float* __restrict__ cond_b, float* __restrict__ cond2) {
    int j = blockIdx.x * 256 + threadIdx.x;
    if (j >= 24000) return;
    int f = j / 12000, jj = j % 12000;
    float s = cond_b[jj];
    const float* wrow = cond_w + (size_t)jj * 60;
    const float* mrow = mgc + f * 60;
    for (int c = 0; c < 60; ++c) s += mrow[c] * wrow[c];
    float v = tanh_f(s);
    int n = f * 200 + jj / 60, cc = jj % 60;
    cond2[n * 60 + cc] = v;
}

// ca_in/ca_g[l][n][co] = cond2[n]·cw[l][co] + cb[l][co] + conv_bias(l,co)   (f32)
__global__ void condadd_kernel(const float* __restrict__ cond2,
                               const float* __restrict__ cw_in, const float* __restrict__ cb_in,
                               const float* __restrict__ cw_g,  const float* __restrict__ cb_g,
                               const float* __restrict__ l0_bin, const float* __restrict__ lb_in,
                               const float* __restrict__ l0_bg,  const float* __restrict__ lb_g,
                               float* __restrict__ ca_in, float* __restrict__ ca_g) {
    int idx = blockIdx.x * 256 + threadIdx.x;
    if (idx >= 10 * 400 * 256) return;
    int co = idx & 255;
    int n  = (idx >> 8) % 400;
    int l  = idx / (400 * 256);
    float si = cb_in[l * 256 + co] + (l == 0 ? l0_bin[co] : lb_in[(l - 1) * 256 + co]);
    float sg = cb_g [l * 256 + co] + (l == 0 ? l0_bg [co] : lb_g [(l - 1) * 256 + co]);
    const float* cn = cond2 + n * 60;
    const float* wi = cw_in + (size_t)(l * 256 + co) * 60;
    const float* wg = cw_g  + (size_t)(l * 256 + co) * 60;
    for (int c = 0; c < 60; ++c) {
        float cv = cn[c];
        si += cv * wi[c];
        sg += cv * wg[c];
    }
    ca_in[idx] = si;
    ca_g[idx]  = sg;
}

// Wg[l][conv][co][k*256+ci] = bf16(lw_conv[l][co][ci][k])
__global__ void wreorder_kernel(const float* __restrict__ lw_in, const float* __restrict__ lw_g,
                                const float* __restrict__ lw_r, u16* __restrict__ Wg) {
    int idx = blockIdx.x * 256 + threadIdx.x;
    if (idx >= 9 * 256 * 512) return;
    int kk = idx & 511;
    int co = (idx >> 9) & 255;
    int l  = idx >> 17;
    int k = kk >> 8, ci = kk & 255;
    size_t src = ((size_t)(l * 256 + co) * 256 + ci) * 2 + k;
    size_t dst = (size_t)l * 3 * 131072 + (size_t)co * 512 + kk;
    Wg[dst]              = f2bf(lw_in[src]);
    Wg[dst + 131072]     = f2bf(lw_g[src]);
    Wg[dst + 2 * 131072] = f2bf(lw_r[src]);
}

// Layer 0 (full f32 math): Y0[n_local][t][ci] bf16, t in [0,512)
__global__ void l0_kernel(const float* __restrict__ signal,
                          const float* __restrict__ l0_win, const float* __restrict__ l0_wg,
                          const float* __restrict__ l0_wr,  const float* __restrict__ l0_br,
                          const float* __restrict__ ca_in0, const float* __restrict__ ca_g0,
                          u16* __restrict__ Y0, int n_start) {
    int b = blockIdx.x;
    int tg = b & 127, n_local = b >> 7;
    int n = n_start + n_local;
    int ci = threadIdx.x;
    float wi0 = l0_win[ci * 2], wi1 = l0_win[ci * 2 + 1];
    float wg0 = l0_wg [ci * 2], wg1 = l0_wg [ci * 2 + 1];
    float wr0 = l0_wr [ci * 2], wr1 = l0_wr [ci * 2 + 1];
    float cain = ca_in0[n * 256 + ci], cag = ca_g0[n * 256 + ci], br = l0_br[ci];
    for (int i = 0; i < 4; ++i) {
        int t = tg * 4 + i;
        float s0 = signal[n + 2 * t];
        float s1 = signal[n + 2 * t + 1];
        float vin = wi0 * s0 + wi1 * s1 + cain;
        float vg  = wg0 * s0 + wg1 * s1 + cag;
        float vr  = wr0 * s0 + wr1 * s1 + br;
        float o = (tanh_f(vin) * sigm(vg) + vr) * SQRT_HALF;
        Y0[((size_t)n_local * 512 + t) * 256 + ci] = f2bf(o);
    }
}

// Fused 3-conv GEMM + gating for layers 1..9.
// A: [M,512] bf16 row-major. Wg: [3][256][512] bf16. Out: Y [M,256] bf16.
// 256 threads, tile 128M x 64co x 3conv, BK=64.
// Staging via global_load_lds (16B/lane); LDS unpadded (stride 64 el) with
// XOR chunk swizzle: slot = chunk ^ (row & 7), applied on the GLOBAL address
// at stage time (LDS dest is wave-uniform + lane*16, so the source is permuted).
__global__ __launch_bounds__(256) void gemm_layer_kernel(
        const u16* __restrict__ A, const u16* __restrict__ Wg,
        const float* __restrict__ ca_in, const float* __restrict__ ca_g,
        const float* __restrict__ br, u16* __restrict__ Y,
        int M, int lg, int n_start) {
    __shared__ u16 Alds[128 * 64];   // 16 KB
    __shared__ u16 Blds[192 * 64];   // 24 KB
    int m0  = blockIdx.x * 128;
    int co0 = blockIdx.y * 64;
    int tid = threadIdx.x;
    int lane = tid & 63, wave = tid >> 6;
    int wm = wave & 1, wc = wave >> 1;
    int q = lane >> 4, r16 = lane & 15;

    // staging lane geometry: each wave-instruction covers 8 tile rows x 8 chunks(16B)
    int rr = lane >> 3;          // 0..7 row within segment
    int cch = lane & 7;          // chunk slot within row
    int csw = cch ^ rr;          // swizzled source chunk

    f32x4 acc[3][4][2] = {};

    for (int kt = 0; kt < 8; ++kt) {
        // stage A tile [128][64]: 16 segments of 8 rows; wave handles 4
        #pragma unroll
        for (int j = 0; j < 4; ++j) {
            int seg = wave * 4 + j;
            int m = m0 + seg * 8 + rr;
            int msafe = m < M ? m : (M - 1);
            GLD_LDS16(A + (size_t)msafe * 512 + kt * 64 + csw * 8, &Alds[seg * 512]);
        }
        // stage B tiles [192][64]: 24 segments; wave handles 6
        #pragma unroll
        for (int j = 0; j < 6; ++j) {
            int seg = wave * 6 + j;
            int brow = seg * 8 + rr;
            int conv = brow >> 6, col = brow & 63;
            GLD_LDS16(Wg + ((size_t)conv * 256 + co0 + col) * 512 + kt * 64 + csw * 8,
                      &Blds[seg * 512]);
        }
        __syncthreads();
        #pragma unroll
        for (int ks = 0; ks < 2; ++ks) {
            int kc = ks * 4 + q;     // 16B chunk index within row
            bf16x8 af[4], bfr[3][2];
            #pragma unroll
            for (int ms = 0; ms < 4; ++ms) {
                int row = wm * 64 + ms * 16 + r16;
                af[ms] = *(const bf16x8*)(&Alds[row * 64 + (kc ^ (row & 7)) * 8]);
            }
            #pragma unroll
            for (int cv = 0; cv < 3; ++cv)
                #pragma unroll
                for (int cs = 0; cs < 2; ++cs) {
                    int row = cv * 64 + wc * 32 + cs * 16 + r16;
                    bfr[cv][cs] = *(const bf16x8*)(&Blds[row * 64 + (kc ^ (row & 7)) * 8]);
                }
            #pragma unroll
            for (int cv = 0; cv < 3; ++cv)
                #pragma unroll
                for (int ms = 0; ms < 4; ++ms)
                    #pragma unroll
                    for (int cs = 0; cs < 2; ++cs)
                        acc[cv][ms][cs] = __builtin_amdgcn_mfma_f32_16x16x32_bf16(
                            af[ms], bfr[cv][cs], acc[cv][ms][cs], 0, 0, 0);
        }
        __syncthreads();
    }

    // epilogue: out = (tanh(in+ca_in) * sigmoid(g+ca_g) + r + br) * sqrt(0.5)
    #pragma unroll
    for (int ms = 0; ms < 4; ++ms) {
        #pragma unroll
        for (int reg = 0; reg < 4; ++reg) {
            int m = m0 + wm * 64 + ms * 16 + q * 4 + reg;
            if (m >= M) continue;
            int n = n_start + (m >> lg);
            #pragma unroll
            for (int cs = 0; cs < 2; ++cs) {
                int co = co0 + wc * 32 + cs * 16 + r16;
                float vin = acc[0][ms][cs][reg] + ca_in[n * 256 + co];
                float vg  = acc[1][ms][cs][reg] + ca_g [n * 256 + co];
                float vr  = acc[2][ms][cs][reg] + br[co];
                float o = (tanh_f(vin) * sigm(vg) + vr) * SQRT_HALF;
                Y[(size_t)m * 256 + co] = f2bf(o);
            }
        }
    }
}

// Head: pre = relu(Y9 @ pre_w.T + pre_b); mean/std/logits = pre @ W.T + b  (f32 math)
__global__ __launch_bounds__(256) void head_kernel(
        const u16* __restrict__ Y9, const float* __restrict__ pre_w, const float* __restrict__ pre_b,
        const float* __restrict__ mean_w, const float* __restrict__ mean_b,
        const float* __restrict__ std_w,  const float* __restrict__ std_b,
        const float* __restrict__ logit_w, const float* __restrict__ logit_b,
        float* __restrict__ out, int n_start) {
    __shared__ float xin[256];
    __shared__ float pre[256];
    int n_local = blockIdx.x;
    int n = n_start + n_local;
    int t = threadIdx.x;
    xin[t] = bf2f(Y9[(size_t)n_local * 256 + t]);
    __syncthreads();
    float s = pre_b[t];
    const float* wrow = pre_w + (size_t)t * 256;
    for (int c = 0; c < 256; ++c) s += xin[c] * wrow[c];
    pre[t] = fmaxf(s, 0.f);
    __syncthreads();
    if (t < 30) {
        int head = t / 10, mix = t % 10;
        const float* w  = head == 0 ? mean_w : (head == 1 ? std_w : logit_w);
        const float* bb = head == 0 ? mean_b : (head == 1 ? std_b : logit_b);
        float s2 = bb[mix];
        const float* wr = w + mix * 256;
        for (int c = 0; c < 256; ++c) s2 += pre[c] * wr[c];
        out[head * 4000 + n * 10 + mix] = s2;
    }
}

extern "C" void kernel_launch(void* const* d_in, const int* in_sizes, int n_in,
                              void* d_out, int out_size, void* d_ws, size_t ws_size,
                              hipStream_t stream) {
    const float* signal  = (const float*)d_in[0];
    const float* mgc     = (const float*)d_in[1];
    const float* cond_w  = (const float*)d_in[2];
    const float* cond_b  = (const float*)d_in[3];
    const float* l0_win  = (const float*)d_in[4];
    const float* l0_bin  = (const float*)d_in[5];
    const float* l0_wg   = (const float*)d_in[6];
    const float* l0_bg   = (const float*)d_in[7];
    const float* l0_wr   = (const float*)d_in[8];
    const float* l0_br   = (const float*)d_in[9];
    const float* lw_in   = (const float*)d_in[10];
    const float* lb_in   = (const float*)d_in[11];
    const float* lw_g    = (const float*)d_in[12];
    const float* lb_g    = (const float*)d_in[13];
    const float* lw_r    = (const float*)d_in[14];
    const float* lb_r    = (const float*)d_in[15];
    const float* cw_in   = (const float*)d_in[16];
    const float* cb_in   = (const float*)d_in[17];
    const float* cw_g    = (const float*)d_in[18];
    const float* cb_g    = (const float*)d_in[19];
    const float* pre_w   = (const float*)d_in[20];
    const float* pre_b   = (const float*)d_in[21];
    const float* mean_w  = (const float*)d_in[22];
    const float* mean_b  = (const float*)d_in[23];
    const float* std_w   = (const float*)d_in[24];
    const float* std_b   = (const float*)d_in[25];
    const float* logit_w = (const float*)d_in[26];
    const float* logit_b = (const float*)d_in[27];
    float* out = (float*)d_out;

    char* p = (char*)d_ws;
    auto alloc = [&](size_t bytes) -> char* {
        char* r = p; p += (bytes + 255) & ~(size_t)255; return r;
    };
    u16*   Wg    = (u16*)alloc(7077888);        // 9*3*256*512 bf16
    float* ca_in = (float*)alloc(4096000);      // 10*400*256 f32
    float* ca_g  = (float*)alloc(4096000);
    float* cond2 = (float*)alloc(96000);        // 400*60 f32
    size_t fixedBytes = (size_t)(p - (char*)d_ws);

    int c = 1;
    while (c < 16 && fixedBytes + (104857600ull + 52428800ull) / c + 4096 > ws_size) c <<= 1;
    u16* bufA = (u16*)alloc(104857600ull / c);
    u16* bufB = (u16*)alloc(52428800ull / c);
    int n_count = 400 / c;

    cond_kernel<<<94, 256, 0, stream>>>(mgc, cond_w, cond_b, cond2);
    condadd_kernel<<<4000, 256, 0, stream>>>(cond2, cw_in, cb_in, cw_g, cb_g,
                                             l0_bin, lb_in, l0_bg, lb_g, ca_in, ca_g);
    wreorder_kernel<<<4608, 256, 0, stream>>>(lw_in, lw_g, lw_r, Wg);

    for (int ch = 0; ch < c; ++ch) {
        int n_start = ch * n_count;
        l0_kernel<<<n_count * 128, 256, 0, stream>>>(signal, l0_win, l0_wg, l0_wr, l0_br,
                                                     ca_in, ca_g, bufA, n_start);
        u16* src = bufA;
        u16* dst = bufB;
        for (int layer = 1; layer <= 9; ++layer) {
            int lg = 9 - layer;          // L_out = 1 << lg
            int M = n_count << lg;
            dim3 grid((M + 127) / 128, 4);
            gemm_layer_kernel<<<grid, 256, 0, stream>>>(
                src, Wg + (size_t)(layer - 1) * 3 * 131072,
                ca_in + (size_t)layer * 102400, ca_g + (size_t)layer * 102400,
                lb_r + (layer - 1) * 256, dst, M, lg, n_start);
            u16* tswap = src; src = dst; dst = tswap;
        }
        head_kernel<<<n_count, 256, 0, stream>>>(src, pre_w, pre_b, mean_w, mean_b,
                                                 std_w, std_b, logit_w, logit_b, out, n_start);
    }
}

// Round 6
// 597.179 us; speedup vs baseline: 1.8225x; 1.0651x over previous
//
#include <hip/hip_runtime.h>

typedef unsigned short u16;
using bf16x8 = __attribute__((ext_vector_type(8))) short;
using f32x4  = __attribute__((ext_vector_type(4))) float;

#define SQRT_HALF 0.70710678118f

__device__ __forceinline__ u16 f2bf(float f) {
    union { float f; unsigned int i; } x; x.f = f;
    unsigned int i = x.i;
    unsigned int r = (i + 0x7FFFu + ((i >> 16) & 1u)) >> 16;
    return (u16)r;
}
__device__ __forceinline__ float bf2f(u16 u) {
    union { unsigned int i; float f; } x; x.i = ((unsigned int)u) << 16; return x.f;
}
__device__ __forceinline__ float sigm(float x) { return 1.0f / (1.0f + __expf(-x)); }
__device__ __forceinline__ float tanh_f(float x) {
    float cx = fminf(fmaxf(x, -12.f), 12.f);
    float e = __expf(2.f * cx);
    return (e - 1.f) / (e + 1.f);
}

// cond2[n][c] = tanh(mgc @ cond_w.T + cond_b) reshaped [400,60]  (all f32)
__global__ void cond_kernel(const float* __restrict__ mgc, const float* __restrict__ cond_w,
                            const float* __restrict__ cond_b, float* __restrict__ cond2) {
    int j = blockIdx.x * 256 + threadIdx.x;
    if (j >= 24000) return;
    int f = j / 12000, jj = j % 12000;
    float s = cond_b[jj];
    const float* wrow = cond_w + (size_t)jj * 60;
    const float* mrow = mgc + f * 60;
    for (int c = 0; c < 60; ++c) s += mrow[c] * wrow[c];
    float v = tanh_f(s);
    int n = f * 200 + jj / 60, cc = jj % 60;
    cond2[n * 60 + cc] = v;
}

// ca_in/ca_g[l][n][co] = cond2[n]·cw[l][co] + cb[l][co] + conv_bias(l,co)   (f32)
__global__ void condadd_kernel(const float* __restrict__ cond2,
                               const float* __restrict__ cw_in, const float* __restrict__ cb_in,
                               const float* __restrict__ cw_g,  const float* __restrict__ cb_g,
                               const float* __restrict__ l0_bin, const float* __restrict__ lb_in,
                               const float* __restrict__ l0_bg,  const float* __restrict__ lb_g,
                               float* __restrict__ ca_in, float* __restrict__ ca_g) {
    int idx = blockIdx.x * 256 + threadIdx.x;
    if (idx >= 10 * 400 * 256) return;
    int co = idx & 255;
    int n  = (idx >> 8) % 400;
    int l  = idx / (400 * 256);
    float si = cb_in[l * 256 + co] + (l == 0 ? l0_bin[co] : lb_in[(l - 1) * 256 + co]);
    float sg = cb_g [l * 256 + co] + (l == 0 ? l0_bg [co] : lb_g [(l - 1) * 256 + co]);
    const float* cn = cond2 + n * 60;
    const float* wi = cw_in + (size_t)(l * 256 + co) * 60;
    const float* wg = cw_g  + (size_t)(l * 256 + co) * 60;
    for (int c = 0; c < 60; ++c) {
        float cv = cn[c];
        si += cv * wi[c];
        sg += cv * wg[c];
    }
    ca_in[idx] = si;
    ca_g[idx]  = sg;
}

// Wg[l][conv][co][k*256+ci] = bf16(lw_conv[l][co][ci][k])
__global__ void wreorder_kernel(const float* __restrict__ lw_in, const float* __restrict__ lw_g,
                                const float* __restrict__ lw_r, u16* __restrict__ Wg) {
    int idx = blockIdx.x * 256 + threadIdx.x;
    if (idx >= 9 * 256 * 512) return;
    int kk = idx & 511;
    int co = (idx >> 9) & 255;
    int l  = idx >> 17;
    int k = kk >> 8, ci = kk & 255;
    size_t src = ((size_t)(l * 256 + co) * 256 + ci) * 2 + k;
    size_t dst = (size_t)l * 3 * 131072 + (size_t)co * 512 + kk;
    Wg[dst]              = f2bf(lw_in[src]);
    Wg[dst + 131072]     = f2bf(lw_g[src]);
    Wg[dst + 2 * 131072] = f2bf(lw_r[src]);
}

// Layer 0 (full f32 math): Y0[n_local][t][ci] bf16, t in [0,512)
__global__ void l0_kernel(const float* __restrict__ signal,
                          const float* __restrict__ l0_win, const float* __restrict__ l0_wg,
                          const float* __restrict__ l0_wr,  const float* __restrict__ l0_br,
                          const float* __restrict__ ca_in0, const float* __restrict__ ca_g0,
                          u16* __restrict__ Y0, int n_start) {
    int b = blockIdx.x;
    int tg = b & 127, n_local = b >> 7;
    int n = n_start + n_local;
    int ci = threadIdx.x;
    float wi0 = l0_win[ci * 2], wi1 = l0_win[ci * 2 + 1];
    float wg0 = l0_wg [ci * 2], wg1 = l0_wg [ci * 2 + 1];
    float wr0 = l0_wr [ci * 2], wr1 = l0_wr [ci * 2 + 1];
    float cain = ca_in0[n * 256 + ci], cag = ca_g0[n * 256 + ci], br = l0_br[ci];
    for (int i = 0; i < 4; ++i) {
        int t = tg * 4 + i;
        float s0 = signal[n + 2 * t];
        float s1 = signal[n + 2 * t + 1];
        float vin = wi0 * s0 + wi1 * s1 + cain;
        float vg  = wg0 * s0 + wg1 * s1 + cag;
        float vr  = wr0 * s0 + wr1 * s1 + br;
        float o = (tanh_f(vin) * sigm(vg) + vr) * SQRT_HALF;
        Y0[((size_t)n_local * 512 + t) * 256 + ci] = f2bf(o);
    }
}

// Fused 3-conv GEMM + gating for layers 1..9 — software-pipelined K-loop.
// A: [M,512] bf16 row-major. Wg: [3][256][512] bf16. Out: Y [M,256] bf16.
// Tile 128M x 64co x 3conv, BK=64, LDS ping-pong (unpadded, XOR chunk swizzle).
// Raw s_barrier (no __syncthreads) so the kt+1 register prefetch is never
// drained by a vmcnt(0); its vmcnt waits land at the ds_write AFTER compute.
__global__ __launch_bounds__(256, 2) void gemm_layer_kernel(
        const u16* __restrict__ A, const u16* __restrict__ Wg,
        const float* __restrict__ ca_in, const float* __restrict__ ca_g,
        const float* __restrict__ br, u16* __restrict__ Y,
        int M, int lg, int n_start) {
    __shared__ u16 Alds[2][128 * 64];   // 2 x 16 KB
    __shared__ u16 Blds[2][192 * 64];   // 2 x 24 KB
    int m0  = blockIdx.x * 128;
    int co0 = blockIdx.y * 64;
    int tid = threadIdx.x;
    int lane = tid & 63, wave = tid >> 6;
    int wm = wave & 1, wc = wave >> 1;
    int q = lane >> 4, r16 = lane & 15;

    // staging geometry: per thread 4 A-chunks + 6 B-chunks (uint4 = 8 bf16)
    const u16* agp[4]; int alof[4];
    #pragma unroll
    for (int i = 0; i < 4; ++i) {
        int chunk = tid + i * 256;
        int row = chunk >> 3, c8 = chunk & 7;
        int m = m0 + row;
        int msafe = m < M ? m : (M - 1);
        agp[i] = A + (size_t)msafe * 512 + c8 * 8;
        alof[i] = row * 64 + ((c8 ^ (row & 7)) * 8);
    }
    const u16* bgp[6]; int blof[6];
    #pragma unroll
    for (int i = 0; i < 6; ++i) {
        int chunk = tid + i * 256;
        int row = chunk >> 3, c8 = chunk & 7;
        int conv = row >> 6, col = row & 63;
        bgp[i] = Wg + ((size_t)conv * 256 + co0 + col) * 512 + c8 * 8;
        blof[i] = row * 64 + ((c8 ^ (row & 7)) * 8);
    }

    uint4 ra[4], rb[6];
    // prologue: load kt=0, write to buffer 0
    #pragma unroll
    for (int i = 0; i < 4; ++i) ra[i] = *(const uint4*)(agp[i]);
    #pragma unroll
    for (int i = 0; i < 6; ++i) rb[i] = *(const uint4*)(bgp[i]);
    #pragma unroll
    for (int i = 0; i < 4; ++i) *(uint4*)(&Alds[0][alof[i]]) = ra[i];
    #pragma unroll
    for (int i = 0; i < 6; ++i) *(uint4*)(&Blds[0][blof[i]]) = rb[i];
    asm volatile("s_waitcnt lgkmcnt(0)\n\ts_barrier" ::: "memory");

    f32x4 acc[3][4][2] = {};

    for (int kt = 0; kt < 8; ++kt) {
        int cur = kt & 1;
        // issue prefetch for kt+1 (completes during compute below)
        if (kt < 7) {
            #pragma unroll
            for (int i = 0; i < 4; ++i) ra[i] = *(const uint4*)(agp[i] + (kt + 1) * 64);
            #pragma unroll
            for (int i = 0; i < 6; ++i) rb[i] = *(const uint4*)(bgp[i] + (kt + 1) * 64);
        }
        // compute kt from LDS[cur]
        #pragma unroll
        for (int ks = 0; ks < 2; ++ks) {
            int kc = ks * 4 + q;
            bf16x8 af[4], bfr[3][2];
            #pragma unroll
            for (int ms = 0; ms < 4; ++ms) {
                int row = wm * 64 + ms * 16 + r16;
                af[ms] = *(const bf16x8*)(&Alds[cur][row * 64 + (kc ^ (row & 7)) * 8]);
            }
            #pragma unroll
            for (int cv = 0; cv < 3; ++cv)
                #pragma unroll
                for (int cs = 0; cs < 2; ++cs) {
                    int row = cv * 64 + wc * 32 + cs * 16 + r16;
                    bfr[cv][cs] = *(const bf16x8*)(&Blds[cur][row * 64 + (kc ^ (row & 7)) * 8]);
                }
            #pragma unroll
            for (int cv = 0; cv < 3; ++cv)
                #pragma unroll
                for (int ms = 0; ms < 4; ++ms)
                    #pragma unroll
                    for (int cs = 0; cs < 2; ++cs)
                        acc[cv][ms][cs] = __builtin_amdgcn_mfma_f32_16x16x32_bf16(
                            af[ms], bfr[cv][cs], acc[cv][ms][cs], 0, 0, 0);
        }
        // all waves done reading LDS[cur]; LDS[cur^1] was last read in kt-1
        asm volatile("s_barrier" ::: "memory");
        if (kt < 7) {
            #pragma unroll
            for (int i = 0; i < 4; ++i) *(uint4*)(&Alds[cur ^ 1][alof[i]]) = ra[i];
            #pragma unroll
            for (int i = 0; i < 6; ++i) *(uint4*)(&Blds[cur ^ 1][blof[i]]) = rb[i];
        }
        // make writes visible; vmcnt NOT drained (no outstanding prefetch crossing here)
        asm volatile("s_waitcnt lgkmcnt(0)\n\ts_barrier" ::: "memory");
    }

    // epilogue: out = (tanh(in+ca_in) * sigmoid(g+ca_g) + r + br) * sqrt(0.5)
    #pragma unroll
    for (int ms = 0; ms < 4; ++ms) {
        #pragma unroll
        for (int reg = 0; reg < 4; ++reg) {
            int m = m0 + wm * 64 + ms * 16 + q * 4 + reg;
            if (m >= M) continue;
            int n = n_start + (m >> lg);
            #pragma unroll
            for (int cs = 0; cs < 2; ++cs) {
                int co = co0 + wc * 32 + cs * 16 + r16;
                float vin = acc[0][ms][cs][reg] + ca_in[n * 256 + co];
                float vg  = acc[1][ms][cs][reg] + ca_g [n * 256 + co];
                float vr  = acc[2][ms][cs][reg] + br[co];
                float o = (tanh_f(vin) * sigm(vg) + vr) * SQRT_HALF;
                Y[(size_t)m * 256 + co] = f2bf(o);
            }
        }
    }
}

// Head: pre = relu(Y9 @ pre_w.T + pre_b); mean/std/logits = pre @ W.T + b  (f32 math)
__global__ __launch_bounds__(256) void head_kernel(
        const u16* __restrict__ Y9, const float* __restrict__ pre_w, const float* __restrict__ pre_b,
        const float* __restrict__ mean_w, const float* __restrict__ mean_b,
        const float* __restrict__ std_w,  const float* __restrict__ std_b,
        const float* __restrict__ logit_w, const float* __restrict__ logit_b,
        float* __restrict__ out, int n_start) {
    __shared__ float xin[256];
    __shared__ float pre[256];
    int n_local = blockIdx.x;
    int n = n_start + n_local;
    int t = threadIdx.x;
    xin[t] = bf2f(Y9[(size_t)n_local * 256 + t]);
    __syncthreads();
    float s = pre_b[t];
    const float* wrow = pre_w + (size_t)t * 256;
    for (int c = 0; c < 256; ++c) s += xin[c] * wrow[c];
    pre[t] = fmaxf(s, 0.f);
    __syncthreads();
    if (t < 30) {
        int head = t / 10, mix = t % 10;
        const float* w  = head == 0 ? mean_w : (head == 1 ? std_w : logit_w);
        const float* bb = head == 0 ? mean_b : (head == 1 ? std_b : logit_b);
        float s2 = bb[mix];
        const float* wr = w + mix * 256;
        for (int c = 0; c < 256; ++c) s2 += pre[c] * wr[c];
        out[head * 4000 + n * 10 + mix] = s2;
    }
}

extern "C" void kernel_launch(void* const* d_in, const int* in_sizes, int n_in,
                              void* d_out, int out_size, void* d_ws, size_t ws_size,
                              hipStream_t stream) {
    const float* signal  = (const float*)d_in[0];
    const float* mgc     = (const float*)d_in[1];
    const float* cond_w  = (const float*)d_in[2];
    const float* cond_b  = (const float*)d_in[3];
    const float* l0_win  = (const float*)d_in[4];
    const float* l0_bin  = (const float*)d_in[5];
    const float* l0_wg   = (const float*)d_in[6];
    const float* l0_bg   = (const float*)d_in[7];
    const float* l0_wr   = (const float*)d_in[8];
    const float* l0_br   = (const float*)d_in[9];
    const float* lw_in   = (const float*)d_in[10];
    const float* lb_in   = (const float*)d_in[11];
    const float* lw_g    = (const float*)d_in[12];
    const float* lb_g    = (const float*)d_in[13];
    const float* lw_r    = (const float*)d_in[14];
    const float* lb_r    = (const float*)d_in[15];
    const float* cw_in   = (const float*)d_in[16];
    const float* cb_in   = (const float*)d_in[17];
    const float* cw_g    = (const float*)d_in[18];
    const float* cb_g    = (const float*)d_in[19];
    const float* pre_w   = (const float*)d_in[20];
    const float* pre_b   = (const float*)d_in[21];
    const float* mean_w  = (const float*)d_in[22];
    const float* mean_b  = (const float*)d_in[23];
    const float* std_w   = (const float*)d_in[24];
    const float* std_b   = (const float*)d_in[25];
    const float* logit_w = (const float*)d_in[26];
    const float* logit_b = (const float*)d_in[27];
    float* out = (float*)d_out;

    char* p = (char*)d_ws;
    auto alloc = [&](size_t bytes) -> char* {
        char* r = p; p += (bytes + 255) & ~(size_t)255; return r;
    };
    u16*   Wg    = (u16*)alloc(7077888);        // 9*3*256*512 bf16
    float* ca_in = (float*)alloc(4096000);      // 10*400*256 f32
    float* ca_g  = (float*)alloc(4096000);
    float* cond2 = (float*)alloc(96000);        // 400*60 f32
    size_t fixedBytes = (size_t)(p - (char*)d_ws);

    int c = 1;
    while (c < 16 && fixedBytes + (104857600ull + 52428800ull) / c + 4096 > ws_size) c <<= 1;
    u16* bufA = (u16*)alloc(104857600ull / c);
    u16* bufB = (u16*)alloc(52428800ull / c);
    int n_count = 400 / c;

    cond_kernel<<<94, 256, 0, stream>>>(mgc, cond_w, cond_b, cond2);
    condadd_kernel<<<4000, 256, 0, stream>>>(cond2, cw_in, cb_in, cw_g, cb_g,
                                             l0_bin, lb_in, l0_bg, lb_g, ca_in, ca_g);
    wreorder_kernel<<<4608, 256, 0, stream>>>(lw_in, lw_g, lw_r, Wg);

    for (int ch = 0; ch < c; ++ch) {
        int n_start = ch * n_count;
        l0_kernel<<<n_count * 128, 256, 0, stream>>>(signal, l0_win, l0_wg, l0_wr, l0_br,
                                                     ca_in, ca_g, bufA, n_start);
        u16* src = bufA;
        u16* dst = bufB;
        for (int layer = 1; layer <= 9; ++layer) {
            int lg = 9 - layer;          // L_out = 1 << lg
            int M = n_count << lg;
            dim3 grid((M + 127) / 128, 4);
            gemm_layer_kernel<<<grid, 256, 0, stream>>>(
                src, Wg + (size_t)(layer - 1) * 3 * 131072,
                ca_in + (size_t)layer * 102400, ca_g + (size_t)layer * 102400,
                lb_r + (layer - 1) * 256, dst, M, lg, n_start);
            u16* tswap = src; src = dst; dst = tswap;
        }
        head_kernel<<<n_count, 256, 0, stream>>>(src, pre_w, pre_b, mean_w, mean_b,
                                                 std_w, std_b, logit_w, logit_b, out, n_start);
    }
}